// Round 6
// baseline (2874.243 us; speedup 1.0000x reference)
//
#include <hip/hip_runtime.h>

// Neural-ODE RK4, swapped-operand MFMA: z^T = W^T @ h^T.
// 256 blocks x 4 batch rows (all CUs); 16 waves (1024 thr) = 4 waves/SIMD,
// each wave owns 16 hidden cols. DESIGNED FOR THE 128-VGPR BUDGET: wreg[3][8]
// = 96 VGPRs (rounds 2/4/5 all failed to keep 192-384 regs resident; the
// allocator spilled to scratch -> ~110MB L3-latency traffic dominated).
// Layer 0 fp16 in LDS (128 KB, per-wave 8KB col-slice). h-tile [4][256] fp16
// (2 KB, double-buffered), broadcast rows (lanes read row l&3; same-address
// LDS reads free), swizzle SW(r)=(r<<4)^((r&2)<<5) -> conflict-minimal b128.
// Fast lipswish via rcpf. RK4 state fp32 in regs; stores predicated lr<4.

#define T_ 128
#define IN_ 32
#define H_ 256

typedef _Float16 half8 __attribute__((ext_vector_type(8)));
typedef _Float16 half4 __attribute__((ext_vector_type(4)));
typedef float f32x4 __attribute__((ext_vector_type(4)));

__device__ __forceinline__ f32x4 mfma16(half8 a, half8 b, f32x4 c) {
    return __builtin_amdgcn_mfma_f32_16x16x32_f16(a, b, c, 0, 0, 0);
}

__device__ __forceinline__ half4 cvt4(f32x4 v) {
    half4 h;
    h[0] = (_Float16)v[0]; h[1] = (_Float16)v[1];
    h[2] = (_Float16)v[2]; h[3] = (_Float16)v[3];
    return h;
}

__device__ __forceinline__ f32x4 lips4(f32x4 v) {
    f32x4 r;
#pragma unroll
    for (int e = 0; e < 4; ++e) {
        float x = v[e];
        r[e] = 0.909f * x * __builtin_amdgcn_rcpf(1.f + __expf(-x));
    }
    return r;
}

// h-tile read: lane reads row rr=l&3, colbyte = ks*64 + lk*16, phys colbyte
// ^= SW(rr). pe/po decomposition keeps every read base + compile-time imm.
#define RDH(KS, BUF) (*(const half8*)(ht + (BUF) + (((KS) & 1) ? (po + ((KS)-1)*64) : (pe + (KS)*64))))
#define RDA(KS)      (*(const half8*)(w0b + (KS)*1024))

#define LAYER_REG(LYI, BUF) do {                            \
    half8 b0 = RDH(0, BUF), b1 = RDH(1, BUF);               \
    acc0 = mfma16(wreg[LYI][0], b0, acc0); b0 = RDH(2, BUF);\
    acc0 = mfma16(wreg[LYI][1], b1, acc0); b1 = RDH(3, BUF);\
    acc0 = mfma16(wreg[LYI][2], b0, acc0); b0 = RDH(4, BUF);\
    acc0 = mfma16(wreg[LYI][3], b1, acc0); b1 = RDH(5, BUF);\
    acc0 = mfma16(wreg[LYI][4], b0, acc0); b0 = RDH(6, BUF);\
    acc0 = mfma16(wreg[LYI][5], b1, acc0); b1 = RDH(7, BUF);\
    acc0 = mfma16(wreg[LYI][6], b0, acc0);                  \
    acc0 = mfma16(wreg[LYI][7], b1, acc0);                  \
} while (0)

#define LAYER_L0(BUF) do {                                  \
    half8 b0 = RDH(0, BUF), b1 = RDH(1, BUF);               \
    acc0 = mfma16(RDA(0), b0, acc0); b0 = RDH(2, BUF);      \
    acc0 = mfma16(RDA(1), b1, acc0); b1 = RDH(3, BUF);      \
    acc0 = mfma16(RDA(2), b0, acc0); b0 = RDH(4, BUF);      \
    acc0 = mfma16(RDA(3), b1, acc0); b1 = RDH(5, BUF);      \
    acc0 = mfma16(RDA(4), b0, acc0); b0 = RDH(6, BUF);      \
    acc0 = mfma16(RDA(5), b1, acc0); b1 = RDH(7, BUF);      \
    acc0 = mfma16(RDA(6), b0, acc0);                        \
    acc0 = mfma16(RDA(7), b1, acc0);                        \
} while (0)

#define ACC_INIT(LY) do { acc0 = *(const f32x4*)(bias + (LY)*H_ + boff); } while (0)

#define ACT_STORE(BUF) do {                                 \
    half4 s0 = cvt4(lips4(acc0));                           \
    if (lr < 4) *(half4*)(ht + (BUF) + wo0) = s0;           \
    __syncthreads();                                        \
} while (0)

#define STORE_Y(BUF, V0) do {                               \
    half4 s0 = cvt4(V0);                                    \
    if (lr < 4) *(half4*)(ht + (BUF) + wo0) = s0;           \
} while (0)

__global__ __attribute__((amdgpu_flat_work_group_size(1024, 1024), amdgpu_waves_per_eu(4, 4)))
void ncde_kernel(const float* __restrict__ coeffs,
                 const float* __restrict__ times,
                 const float* __restrict__ W_init,
                 const float* __restrict__ b_init,
                 const float* __restrict__ Wf,
                 const float* __restrict__ bfv,
                 _Float16* __restrict__ ybuf)
{
    extern __shared__ char smem[];
    _Float16* w0   = (_Float16*)smem;                 // 128 KiB [ct16][ks8][ln64][8]
    char*     ht   = smem + 131072;                   // 2 x 2 KiB swizzled [4][256] f16
    float*    bias = (float*)(smem + 131072 + 4096);  // [4][256] f32

    const int tid = threadIdx.x;            // 0..1023
    const int l   = tid & 63;
    const int w   = tid >> 6;               // wave 0..15, owns cols [w*16, w*16+16)
    const int lr  = l & 15;                 // B-frag col (batch slot; valid 0..3)
    const int lk  = l >> 4;                 // 0..3
    const int rr  = l & 3;                  // physical batch row for reads
    const int bc  = blockIdx.x;             // 0..255, batch rows bc*4..bc*4+3

    const int SWr = (rr << 4) ^ ((rr & 2) << 5);
    const int rb  = rr*512 + ((lk*16) ^ (SWr & 0x30));
    const int pe  = rb + (SWr & 0x40);
    const int po  = rb + (64 ^ (SWr & 0x40));
    // write offset (used only when lr<4, row=lr): col byte = w*32 + lk*8
    const int SWw = ((lr & 3) << 4) ^ (((lr & 3) & 2) << 5);
    const int wo0 = (lr & 3)*512 + (((w*32) | (lk*8)) ^ SWw);
    const int boff = w*16 + lk*4;
    const char* w0b = (const char*)w0 + (size_t)w * 8192 + l * 16;

    // ---------------- prologue ----------------
    if (tid < 4 * H_) bias[tid] = bfv[tid];

    // layer-0 W^T A-frags: entry e=(ct*8+ks)*64+ln, lane elems j:
    // Wf[0][ks*32+(ln>>4)*8+j][ct*16+(ln&15)]
    for (int e = tid; e < 8192; e += 1024) {
        int ct = e >> 9, ks = (e >> 6) & 7, ln = e & 63;
        const float* src = Wf + (size_t)(ks*32 + ((ln >> 4) << 3)) * H_ + ct*16 + (ln & 15);
        half8 v;
#pragma unroll
        for (int j = 0; j < 8; ++j) v[j] = (_Float16)src[(size_t)j * H_];
        *(half8*)(w0 + (size_t)e * 8) = v;
    }

    // layers 1..3 W^T A-frags in regs (96 VGPRs): this wave's 16 cols
    half8 wreg[3][8];
#pragma unroll
    for (int ly = 0; ly < 3; ++ly)
#pragma unroll
        for (int ks = 0; ks < 8; ++ks) {
            const float* src = Wf + ((size_t)(ly + 1) * H_ + ks*32 + lk*8) * H_
                                  + w*16 + lr;
            half8 v;
#pragma unroll
            for (int j = 0; j < 8; ++j) v[j] = (_Float16)src[(size_t)j * H_];
            wreg[ly][ks] = v;
        }

    // y0 = coeffs[:,0,:] @ W_init + b_init (fp32 VALU, one-time)
    // lane holds y[batch=bc*4+rr][w*16 + lk*4 + r]; lanes lr>=4 hold dups
    f32x4 y0v;
    {
        const float* crow = coeffs + (size_t)(bc*4 + rr) * (T_ * IN_);
        f32x4 acc;
#pragma unroll
        for (int r = 0; r < 4; ++r) {
            int col = w*16 + lk*4 + r;
            float s = b_init[col];
            for (int k = 0; k < IN_; ++k)
                s += crow[k] * W_init[(size_t)k * H_ + col];
            acc[r] = s;
        }
        y0v = acc;
    }

    STORE_Y(0, y0v);
    __syncthreads();
    {   // dump t=0: rows 0-3 (2 KB), unswizzled, coalesced 16B/thread
        if (tid < 128) {
            int drow = tid >> 5, dcb = (tid & 31) * 16;
            int dsw = (drow << 4) ^ ((drow & 2) << 5);
            uint4 v = *(const uint4*)(ht + drow*512 + (dcb ^ dsw));
            char* dst = (char*)ybuf + ((size_t)((bc >> 2) * T_)) * 8192
                        + (bc & 3) * 2048 + tid * 16;
            *(uint4*)dst = v;
        }
    }

#pragma unroll 1
    for (int st = 0; st < T_ - 1; ++st) {
        float dt = times[st + 1] - times[st];
        f32x4 ks0;
#pragma unroll 1
        for (int s = 0; s < 4; ++s) {
            f32x4 acc0;
            ACC_INIT(0); LAYER_L0(0);        ACT_STORE(2048);
            ACC_INIT(1); LAYER_REG(0, 2048); ACT_STORE(0);
            ACC_INIT(2); LAYER_REG(1, 0);    ACT_STORE(2048);
            ACC_INIT(3); LAYER_REG(2, 2048);            // k = acc (bias folded)
            if (s == 0)      ks0 = acc0;
            else if (s < 3)  ks0 += 2.f*acc0;
            else             ks0 += acc0;
            if (s < 3) {
                float cy = (s == 2) ? dt : 0.5f * dt;
                STORE_Y(0, y0v + cy*acc0);
            } else {
                float c6 = dt * (1.f / 6.f);
                y0v += c6*ks0;
                STORE_Y(0, y0v);
            }
            __syncthreads();
        }
        {   // dump y at t = st+1
            if (tid < 128) {
                int drow = tid >> 5, dcb = (tid & 31) * 16;
                int dsw = (drow << 4) ^ ((drow & 2) << 5);
                uint4 v = *(const uint4*)(ht + drow*512 + (dcb ^ dsw));
                char* dst = (char*)ybuf + ((size_t)((bc >> 2) * T_ + st + 1)) * 8192
                            + (bc & 3) * 2048 + tid * 16;
                *(uint4*)dst = v;
            }
        }
    }
}

// out^T = Wd^T @ y^T per (16-batch, t) tile. One wave per (bc16, 16 t-steps).
// ybuf layout: [64 superblock][T][16 rows][256] f16 (4 ncde blocks interleave).
__global__ __launch_bounds__(64)
void proj_kernel(const _Float16* __restrict__ ybuf,
                 const float* __restrict__ Wd,   // [H,32]
                 const float* __restrict__ bd,   // [32]
                 float* __restrict__ out)        // [B,T,32]
{
    const int l  = threadIdx.x;
    const int lr = l & 15, lk = l >> 4;
    const int bc = blockIdx.x;
    const int tg = blockIdx.y;

    half8 wd[2][8];
#pragma unroll
    for (int c = 0; c < 2; ++c)
#pragma unroll
        for (int ks = 0; ks < 8; ++ks) {
            const float* src = Wd + (size_t)(ks*32 + lk*8) * 32 + c*16 + lr;
            half8 v;
#pragma unroll
            for (int j = 0; j < 8; ++j) v[j] = (_Float16)src[(size_t)j * 32];
            wd[c][ks] = v;
        }
    f32x4 bd0 = *(const f32x4*)(bd + lk*4);
    f32x4 bd1 = *(const f32x4*)(bd + 16 + lk*4);

    for (int t = tg*16; t < tg*16 + 16; ++t) {
        const _Float16* yt = ybuf + ((size_t)(bc*T_) + t) * 4096;
        f32x4 a0 = f32x4{0.f,0.f,0.f,0.f}, a1 = f32x4{0.f,0.f,0.f,0.f};
#pragma unroll
        for (int ks = 0; ks < 8; ++ks) {
            half8 b = *(const half8*)(yt + lr*256 + ks*32 + lk*8);
            a0 = mfma16(wd[0][ks], b, a0);
            a1 = mfma16(wd[1][ks], b, a1);
        }
        float* op = out + ((size_t)(bc*16 + lr) * T_ + t) * 32;
        *(f32x4*)(op + lk*4)      = a0 + bd0;
        *(f32x4*)(op + 16 + lk*4) = a1 + bd1;
    }
}

extern "C" void kernel_launch(void* const* d_in, const int* in_sizes, int n_in,
                              void* d_out, int out_size, void* d_ws, size_t ws_size,
                              hipStream_t stream) {
    const float* coeffs = (const float*)d_in[0];
    const float* times  = (const float*)d_in[1];
    const float* W_init = (const float*)d_in[2];
    const float* b_init = (const float*)d_in[3];
    const float* Wf     = (const float*)d_in[4];
    const float* bfv    = (const float*)d_in[5];
    const float* Wd     = (const float*)d_in[6];
    const float* bd     = (const float*)d_in[7];
    _Float16* ybuf = (_Float16*)d_ws;               // 64*128*4096 halfs = 64 MiB
    float* out = (float*)d_out;

    const size_t lds_bytes = 131072 + 4096 + 4096;   // 139,264 B <= 160 KiB
    hipLaunchKernelGGL(ncde_kernel, dim3(256), dim3(1024), lds_bytes, stream,
                       coeffs, times, W_init, b_init, Wf, bfv, ybuf);
    hipLaunchKernelGGL(proj_kernel, dim3(64, 8), dim3(64), 0, stream,
                       ybuf, Wd, bd, out);
}

// Round 7
// 1667.044 us; speedup vs baseline: 1.7242x; 1.7242x over previous
//
#include <hip/hip_runtime.h>

// Neural-ODE RK4, swapped-operand MFMA: z^T = W^T @ h^T.
// 256 blocks x 4 batch rows (all CUs); 8 waves (512 thr) = 2 waves/SIMD,
// each wave owns 32 hidden cols; wreg[3][2][8] = 192 VGPRs.
// ALLOCATOR MODEL (rounds 4/5/6 measured): arch-VGPR budget = 256 / n where
// n = amdgpu_waves_per_eu MIN. n=1 -> 256 regs, zero spill (round 4);
// n=2 -> 128 (round 5, 110MB spill); n=4 -> 64 (round 6, 500MB spill).
// So: amdgpu_waves_per_eu(1,2). 8 waves x 256 regs = full per-CU pool =
// 2 waves/SIMD physical occupancy (m69), which the (1,2) range covers.
// Layer 0 fp16 in LDS (128 KB, per-wave 8KB col-slice). h-tile [4][256] fp16
// (2 KB, double-buffered): B-frag rows 4..15 are broadcast duplicates (lanes
// read row l&3; same-address LDS reads free). Swizzle SW(r)=(r<<4)^((r&2)<<5)
// keeps ds_read_b128 conflict-minimal. Fast lipswish via rcpf.
// RK4 state fp32 in registers; h stores predicated to lr<4.

#define T_ 128
#define IN_ 32
#define H_ 256

typedef _Float16 half8 __attribute__((ext_vector_type(8)));
typedef _Float16 half4 __attribute__((ext_vector_type(4)));
typedef float f32x4 __attribute__((ext_vector_type(4)));

__device__ __forceinline__ f32x4 mfma16(half8 a, half8 b, f32x4 c) {
    return __builtin_amdgcn_mfma_f32_16x16x32_f16(a, b, c, 0, 0, 0);
}

__device__ __forceinline__ half4 cvt4(f32x4 v) {
    half4 h;
    h[0] = (_Float16)v[0]; h[1] = (_Float16)v[1];
    h[2] = (_Float16)v[2]; h[3] = (_Float16)v[3];
    return h;
}

__device__ __forceinline__ f32x4 lips4(f32x4 v) {
    f32x4 r;
#pragma unroll
    for (int e = 0; e < 4; ++e) {
        float x = v[e];
        r[e] = 0.909f * x * __builtin_amdgcn_rcpf(1.f + __expf(-x));
    }
    return r;
}

// h-tile read: lane reads row rr=l&3, colbyte = ks*64 + lk*16, phys colbyte
// ^= SW(rr). pe/po decomposition keeps every read base + compile-time imm.
#define RDH(KS, BUF) (*(const half8*)(ht + (BUF) + (((KS) & 1) ? (po + ((KS)-1)*64) : (pe + (KS)*64))))
#define RDA(C, KS)   (*(const half8*)(w0b + (C)*8192 + (KS)*1024))

#define KSTEP(LYI, KS, BREG) \
    acc0 = mfma16(wreg[LYI][0][KS], BREG, acc0); \
    acc1 = mfma16(wreg[LYI][1][KS], BREG, acc1);

#define LAYER_REG(LYI, BUF) do {                    \
    half8 b0 = RDH(0, BUF), b1 = RDH(1, BUF);       \
    KSTEP(LYI, 0, b0) b0 = RDH(2, BUF);             \
    KSTEP(LYI, 1, b1) b1 = RDH(3, BUF);             \
    KSTEP(LYI, 2, b0) b0 = RDH(4, BUF);             \
    KSTEP(LYI, 3, b1) b1 = RDH(5, BUF);             \
    KSTEP(LYI, 4, b0) b0 = RDH(6, BUF);             \
    KSTEP(LYI, 5, b1) b1 = RDH(7, BUF);             \
    KSTEP(LYI, 6, b0)                               \
    KSTEP(LYI, 7, b1)                               \
} while (0)

#define KSTEP0(KS, BREG) {                              \
    half8 x;                                            \
    x = RDA(0, KS); acc0 = mfma16(x, BREG, acc0);       \
    x = RDA(1, KS); acc1 = mfma16(x, BREG, acc1); }

#define LAYER_L0(BUF) do {                          \
    half8 b0 = RDH(0, BUF), b1 = RDH(1, BUF);       \
    KSTEP0(0, b0) b0 = RDH(2, BUF);                 \
    KSTEP0(1, b1) b1 = RDH(3, BUF);                 \
    KSTEP0(2, b0) b0 = RDH(4, BUF);                 \
    KSTEP0(3, b1) b1 = RDH(5, BUF);                 \
    KSTEP0(4, b0) b0 = RDH(6, BUF);                 \
    KSTEP0(5, b1) b1 = RDH(7, BUF);                 \
    KSTEP0(6, b0)                                   \
    KSTEP0(7, b1)                                   \
} while (0)

#define ACC_INIT(LY) do {                                       \
    acc0 = *(const f32x4*)(biasb + (LY)*1024 + 0);              \
    acc1 = *(const f32x4*)(biasb + (LY)*1024 + 64);             \
} while (0)

#define ACT_STORE(BUF) do {                                     \
    half4 s0 = cvt4(lips4(acc0)), s1 = cvt4(lips4(acc1));       \
    if (lr < 4) {                                               \
        *(half4*)(ht + (BUF) + wo0) = s0;                       \
        *(half4*)(ht + (BUF) + wo1) = s1;                       \
    }                                                           \
    __syncthreads();                                            \
} while (0)

#define STORE_Y(BUF, V0, V1) do {                               \
    half4 s0 = cvt4(V0), s1 = cvt4(V1);                         \
    if (lr < 4) {                                               \
        *(half4*)(ht + (BUF) + wo0) = s0;                       \
        *(half4*)(ht + (BUF) + wo1) = s1;                       \
    }                                                           \
} while (0)

__global__ __attribute__((amdgpu_flat_work_group_size(512, 512), amdgpu_waves_per_eu(1, 2)))
void ncde_kernel(const float* __restrict__ coeffs,
                 const float* __restrict__ times,
                 const float* __restrict__ W_init,
                 const float* __restrict__ b_init,
                 const float* __restrict__ Wf,
                 const float* __restrict__ bfv,
                 _Float16* __restrict__ ybuf)
{
    extern __shared__ char smem[];
    _Float16* w0   = (_Float16*)smem;                 // 128 KiB [ct16][ks8][ln64][8]
    char*     ht   = smem + 131072;                   // 2 x 2 KiB swizzled [4][256] f16
    float*    bias = (float*)(smem + 131072 + 4096);  // [4][256] f32

    const int tid = threadIdx.x;            // 0..511
    const int l   = tid & 63;
    const int w   = tid >> 6;               // wave 0..7, owns cols [w*32, w*32+32)
    const int lr  = l & 15;                 // B-frag col (batch slot; valid 0..3)
    const int lk  = l >> 4;                 // 0..3
    const int rr  = l & 3;                  // physical batch row for reads
    const int bc  = blockIdx.x;             // 0..255, batch rows bc*4..bc*4+3

    const int SWr = (rr << 4) ^ ((rr & 2) << 5);
    const int rb  = rr*512 + ((lk*16) ^ (SWr & 0x30));
    const int pe  = rb + (SWr & 0x40);
    const int po  = rb + (64 ^ (SWr & 0x40));
    // write offsets (used only when lr<4, row=lr): col bytes w*64 + lk*8 (+32)
    const int SWw = ((lr & 3) << 4) ^ (((lr & 3) & 2) << 5);
    const int wo0 = (lr & 3)*512 + (((w*64) | (lk*8)) ^ SWw);
    const int wo1 = wo0 ^ 32;
    const char* w0b   = (const char*)w0 + (size_t)(2*w) * 8192 + l * 16;
    const char* biasb = (const char*)bias + w * 128 + lk * 16;

    // ---------------- prologue ----------------
    for (int i = tid; i < 4 * H_; i += 512) bias[i] = bfv[i];

    // layer-0 W^T A-frags: entry e=(ct*8+ks)*64+ln, lane elems j:
    // Wf[0][ks*32+(ln>>4)*8+j][ct*16+(ln&15)]
    for (int e = tid; e < 8192; e += 512) {
        int ct = e >> 9, ks = (e >> 6) & 7, ln = e & 63;
        const float* src = Wf + (size_t)(ks*32 + ((ln >> 4) << 3)) * H_ + ct*16 + (ln & 15);
        half8 v;
#pragma unroll
        for (int j = 0; j < 8; ++j) v[j] = (_Float16)src[(size_t)j * H_];
        *(half8*)(w0 + (size_t)e * 8) = v;
    }

    // layers 1..3 W^T A-frags in regs (192 VGPRs): this wave's 32 cols
    half8 wreg[3][2][8];
#pragma unroll
    for (int ly = 0; ly < 3; ++ly)
#pragma unroll
        for (int c = 0; c < 2; ++c)
#pragma unroll
            for (int ks = 0; ks < 8; ++ks) {
                const float* src = Wf + ((size_t)(ly + 1) * H_ + ks*32 + lk*8) * H_
                                      + w*32 + c*16 + lr;
                half8 v;
#pragma unroll
                for (int j = 0; j < 8; ++j) v[j] = (_Float16)src[(size_t)j * H_];
                wreg[ly][c][ks] = v;
            }

    // y0 = coeffs[:,0,:] @ W_init + b_init (fp32 VALU, one-time)
    // lane holds y[batch=bc*4+rr][w*32 + c*16 + lk*4 + r]; lanes lr>=4 dups
    f32x4 y0v, y1v;
    {
        const float* crow = coeffs + (size_t)(bc*4 + rr) * (T_ * IN_);
#pragma unroll
        for (int c = 0; c < 2; ++c) {
            f32x4 acc;
#pragma unroll
            for (int r = 0; r < 4; ++r) {
                int col = w*32 + c*16 + lk*4 + r;
                float s = b_init[col];
                for (int k = 0; k < IN_; ++k)
                    s += crow[k] * W_init[(size_t)k * H_ + col];
                acc[r] = s;
            }
            if (c == 0) y0v = acc; else y1v = acc;
        }
    }

    STORE_Y(0, y0v, y1v);
    __syncthreads();
    {   // dump t=0: rows 0-3 (2 KB), unswizzled, coalesced 16B/thread
        if (tid < 128) {
            int drow = tid >> 5, dcb = (tid & 31) * 16;
            int dsw = (drow << 4) ^ ((drow & 2) << 5);
            uint4 v = *(const uint4*)(ht + drow*512 + (dcb ^ dsw));
            char* dst = (char*)ybuf + ((size_t)((bc >> 2) * T_)) * 8192
                        + (bc & 3) * 2048 + tid * 16;
            *(uint4*)dst = v;
        }
    }

#pragma unroll 1
    for (int st = 0; st < T_ - 1; ++st) {
        float dt = times[st + 1] - times[st];
        f32x4 ks0, ks1;
#pragma unroll 1
        for (int s = 0; s < 4; ++s) {
            f32x4 acc0, acc1;
            ACC_INIT(0); LAYER_L0(0);        ACT_STORE(2048);
            ACC_INIT(1); LAYER_REG(0, 2048); ACT_STORE(0);
            ACC_INIT(2); LAYER_REG(1, 0);    ACT_STORE(2048);
            ACC_INIT(3); LAYER_REG(2, 2048);            // k = acc (bias folded)
            if (s == 0)      { ks0 = acc0;       ks1 = acc1; }
            else if (s < 3)  { ks0 += 2.f*acc0;  ks1 += 2.f*acc1; }
            else             { ks0 += acc0;      ks1 += acc1; }
            if (s < 3) {
                float cy = (s == 2) ? dt : 0.5f * dt;
                STORE_Y(0, y0v + cy*acc0, y1v + cy*acc1);
            } else {
                float c6 = dt * (1.f / 6.f);
                y0v += c6*ks0; y1v += c6*ks1;
                STORE_Y(0, y0v, y1v);
            }
            __syncthreads();
        }
        {   // dump y at t = st+1
            if (tid < 128) {
                int drow = tid >> 5, dcb = (tid & 31) * 16;
                int dsw = (drow << 4) ^ ((drow & 2) << 5);
                uint4 v = *(const uint4*)(ht + drow*512 + (dcb ^ dsw));
                char* dst = (char*)ybuf + ((size_t)((bc >> 2) * T_ + st + 1)) * 8192
                            + (bc & 3) * 2048 + tid * 16;
                *(uint4*)dst = v;
            }
        }
    }
}

// out^T = Wd^T @ y^T per (16-batch, t) tile. One wave per (bc16, 16 t-steps).
// ybuf layout: [64 superblock][T][16 rows][256] f16 (4 ncde blocks interleave).
__global__ __launch_bounds__(64)
void proj_kernel(const _Float16* __restrict__ ybuf,
                 const float* __restrict__ Wd,   // [H,32]
                 const float* __restrict__ bd,   // [32]
                 float* __restrict__ out)        // [B,T,32]
{
    const int l  = threadIdx.x;
    const int lr = l & 15, lk = l >> 4;
    const int bc = blockIdx.x;
    const int tg = blockIdx.y;

    half8 wd[2][8];
#pragma unroll
    for (int c = 0; c < 2; ++c)
#pragma unroll
        for (int ks = 0; ks < 8; ++ks) {
            const float* src = Wd + (size_t)(ks*32 + lk*8) * 32 + c*16 + lr;
            half8 v;
#pragma unroll
            for (int j = 0; j < 8; ++j) v[j] = (_Float16)src[(size_t)j * 32];
            wd[c][ks] = v;
        }
    f32x4 bd0 = *(const f32x4*)(bd + lk*4);
    f32x4 bd1 = *(const f32x4*)(bd + 16 + lk*4);

    for (int t = tg*16; t < tg*16 + 16; ++t) {
        const _Float16* yt = ybuf + ((size_t)(bc*T_) + t) * 4096;
        f32x4 a0 = f32x4{0.f,0.f,0.f,0.f}, a1 = f32x4{0.f,0.f,0.f,0.f};
#pragma unroll
        for (int ks = 0; ks < 8; ++ks) {
            half8 b = *(const half8*)(yt + lr*256 + ks*32 + lk*8);
            a0 = mfma16(wd[0][ks], b, a0);
            a1 = mfma16(wd[1][ks], b, a1);
        }
        float* op = out + ((size_t)(bc*16 + lr) * T_ + t) * 32;
        *(f32x4*)(op + lk*4)      = a0 + bd0;
        *(f32x4*)(op + 16 + lk*4) = a1 + bd1;
    }
}

extern "C" void kernel_launch(void* const* d_in, const int* in_sizes, int n_in,
                              void* d_out, int out_size, void* d_ws, size_t ws_size,
                              hipStream_t stream) {
    const float* coeffs = (const float*)d_in[0];
    const float* times  = (const float*)d_in[1];
    const float* W_init = (const float*)d_in[2];
    const float* b_init = (const float*)d_in[3];
    const float* Wf     = (const float*)d_in[4];
    const float* bfv    = (const float*)d_in[5];
    const float* Wd     = (const float*)d_in[6];
    const float* bd     = (const float*)d_in[7];
    _Float16* ybuf = (_Float16*)d_ws;               // 64*128*4096 halfs = 64 MiB
    float* out = (float*)d_out;

    const size_t lds_bytes = 131072 + 4096 + 4096;   // 139,264 B <= 160 KiB
    hipLaunchKernelGGL(ncde_kernel, dim3(256), dim3(512), lds_bytes, stream,
                       coeffs, times, W_init, b_init, Wf, bfv, ybuf);
    hipLaunchKernelGGL(proj_kernel, dim3(64, 8), dim3(64), 0, stream,
                       ybuf, Wd, bd, out);
}